// Round 1
// baseline (400.157 us; speedup 1.0000x reference)
//
#include <hip/hip_runtime.h>

// LNCC multi-scale loss, fp32, shape (4,1,144,144,144), scalar output.
// Separable dilated box-sums: X-pass (compute i,t,i2,t2,it on the fly),
// Y-pass, fused Z-pass + LNCC + reduction.

constexpr int BATCH = 4;
constexpr int DIM   = 144;   // D = H = W = 144

// ---------------- init: out = B * (0.1+0.3+0.6) = 4.0 --------------------
__global__ void k_init_out(float* out) {
    if (threadIdx.x == 0 && blockIdx.x == 0) out[0] = 4.0f;
}

// ---------------- pass 1: dilated box-sum along X ------------------------
// in/tg: (B, D, H, W=144). out: 5 planes of (B, D, H, Wout), plane stride n1.
// x taps: x0 = xo*st + 2*j, j in [0,k)
__global__ void k_pass1_x(const float* __restrict__ in,
                          const float* __restrict__ tg,
                          float* __restrict__ out,
                          int k, int st, int wout, int n1) {
    int idx = blockIdx.x * blockDim.x + threadIdx.x;
    if (idx >= n1) return;
    int xo   = idx % wout;
    int rest = idx / wout;            // (b*D + z)*H + y
    int base = rest * DIM + xo * st;

    float si = 0.f, stt = 0.f, sii = 0.f, st2 = 0.f, sit = 0.f;
    for (int j = 0; j < k; ++j) {
        float a = in[base + 2 * j];
        float b = tg[base + 2 * j];
        si  += a;
        stt += b;
        sii += a * a;
        st2 += b * b;
        sit += a * b;
    }
    out[idx]          = si;
    out[n1 + idx]     = stt;
    out[2 * n1 + idx] = sii;
    out[3 * n1 + idx] = st2;
    out[4 * n1 + idx] = sit;
}

// ---------------- pass 2: dilated box-sum along Y -------------------------
// in: 5 planes (B, D, H=144, Wout), plane stride n1.
// out: 5 planes (B, D, Hout, Wout), plane stride n2.
__global__ void k_pass2_y(const float* __restrict__ in,
                          float* __restrict__ out,
                          int k, int st, int wout, int hout,
                          int n1, int n2) {
    int idx = blockIdx.x * blockDim.x + threadIdx.x;
    if (idx >= n2) return;
    int xo = idx % wout;
    int t  = idx / wout;
    int yo = t % hout;
    int bz = t / hout;                // b*D + z
    int base = (bz * DIM + yo * st) * wout + xo;
    int step = 2 * wout;

    float s0 = 0.f, s1 = 0.f, s2 = 0.f, s3 = 0.f, s4 = 0.f;
    for (int j = 0; j < k; ++j) {
        int o = base + j * step;
        s0 += in[o];
        s1 += in[n1 + o];
        s2 += in[2 * n1 + o];
        s3 += in[3 * n1 + o];
        s4 += in[4 * n1 + o];
    }
    out[idx]          = s0;
    out[n2 + idx]     = s1;
    out[2 * n2 + idx] = s2;
    out[3 * n2 + idx] = s3;
    out[4 * n2 + idx] = s4;
}

// ------------- pass 3: Z box-sum + LNCC + block reduce + atomicAdd --------
// in: 5 planes (B, D=144, Hout, Wout), plane stride n2.
// For each (b, zo, yo, xo): z taps z0 = zo*st + 2*j.
__global__ void k_pass3_lncc(const float* __restrict__ in,
                             float* __restrict__ out,
                             int k, int st, int wout, int hout, int dout,
                             int n2, float inv_numel, float factor, int n3) {
    int idx = blockIdx.x * blockDim.x + threadIdx.x;
    float lncc = 0.f;
    if (idx < n3) {
        int xo = idx % wout;
        int t  = idx / wout;
        int yo = t % hout;
        t /= hout;
        int zo = t % dout;
        int b  = t / dout;
        int base = ((b * DIM + zo * st) * hout + yo) * wout + xo;
        int step = 2 * hout * wout;

        float s0 = 0.f, s1 = 0.f, s2 = 0.f, s3 = 0.f, s4 = 0.f;
        for (int j = 0; j < k; ++j) {
            int o = base + j * step;
            s0 += in[o];
            s1 += in[n2 + o];
            s2 += in[2 * n2 + o];
            s3 += in[3 * n2 + o];
            s4 += in[4 * n2 + o];
        }
        float cross = s4 - s0 * s1 * inv_numel;
        float ivar  = s2 - s0 * s0 * inv_numel;
        float tvar  = s3 - s1 * s1 * inv_numel;
        lncc = (cross * cross) / (ivar * tvar + 1e-5f);
    }

    // block reduction (256 threads = 4 waves of 64)
    float v = lncc;
    for (int off = 32; off > 0; off >>= 1)
        v += __shfl_down(v, off, 64);
    __shared__ float sm[4];
    int lane = threadIdx.x & 63;
    int wid  = threadIdx.x >> 6;
    if (lane == 0) sm[wid] = v;
    __syncthreads();
    if (threadIdx.x == 0) {
        float s = sm[0] + sm[1] + sm[2] + sm[3];
        atomicAdd(out, -factor * s);
    }
}

// --------------------------------------------------------------------------
extern "C" void kernel_launch(void* const* d_in, const int* in_sizes, int n_in,
                              void* d_out, int out_size, void* d_ws, size_t ws_size,
                              hipStream_t stream) {
    const float* input  = (const float*)d_in[0];
    const float* target = (const float*)d_in[1];
    float* out = (float*)d_out;

    // workspace: buf1 = 5 * N1max floats, buf2 = 5 * N2max floats
    // N1max (k=9): 4*144*144*64 = 5,308,416 ; N2max: 4*144*64*64 = 2,359,296
    const int N1MAX = BATCH * DIM * DIM * 64;
    float* buf1 = (float*)d_ws;
    float* buf2 = buf1 + (size_t)5 * N1MAX;

    k_init_out<<<1, 64, 0, stream>>>(out);

    const int scales_k[3]  = {9, 18, 36};
    const int scales_st[3] = {2, 4, 9};
    const int scales_o[3]  = {64, 28, 9};
    const float scales_w[3] = {0.1f, 0.3f, 0.6f};

    const int TB = 256;
    for (int s = 0; s < 3; ++s) {
        int k = scales_k[s], st = scales_st[s], o = scales_o[s];
        int n1 = BATCH * DIM * DIM * o;       // (B, D, H, Wout)
        int n2 = BATCH * DIM * o * o;         // (B, D, Hout, Wout)
        int n3 = BATCH * o * o * o;           // (B, Dout, Hout, Wout)
        float numel = (float)k * (float)k * (float)k;
        float inv_numel = 1.0f / numel;
        float factor = scales_w[s] / (float)(o * o * o);  // w / Nout (per-batch)

        k_pass1_x<<<(n1 + TB - 1) / TB, TB, 0, stream>>>(
            input, target, buf1, k, st, o, n1);
        k_pass2_y<<<(n2 + TB - 1) / TB, TB, 0, stream>>>(
            buf1, buf2, k, st, o, o, n1, n2);
        k_pass3_lncc<<<(n3 + TB - 1) / TB, TB, 0, stream>>>(
            buf2, out, k, st, o, o, o, n2, inv_numel, factor, n3);
    }
}

// Round 2
// 208.485 us; speedup vs baseline: 1.9194x; 1.9194x over previous
//
#include <hip/hip_runtime.h>

// LNCC multi-scale loss, fp32, (4,1,144,144,144) -> scalar.
// Separable dilated box-sums, all compile-time templated:
//   pass1 (X): LDS row staging, coalesced global loads, unrolled taps
//   pass2 (Y): sliding-window recurrence (k=9,18), direct (k=36)
//   pass3 (Z): sliding + fused LNCC (k=9), direct + LNCC (k=18,36)

constexpr int BATCH = 4;
constexpr int DIM   = 144;
constexpr int NROWS = BATCH * DIM * DIM;   // 82944 rows along X
constexpr float EPS = 1e-5f;

__global__ void k_init_out(float* out) {
    if (threadIdx.x == 0 && blockIdx.x == 0) out[0] = 4.0f;
}

// ---------------- pass 1: X box-sum, LDS staged ---------------------------
// Block: 256 threads, ROWS rows of 144. LPR lanes per row (LPR*ROWS==256).
// Rows are contiguous in memory -> staging loads are perfectly coalesced.
template<int K, int ST, int OUT, int ROWS, int LPR>
__global__ void k1_x(const float* __restrict__ in, const float* __restrict__ tg,
                     float* __restrict__ out, int n1)
{
    __shared__ float la[ROWS][DIM + 1];
    __shared__ float lb[ROWS][DIM + 1];
    const int t = threadIdx.x;
    const int gbase = blockIdx.x * (ROWS * DIM);
    #pragma unroll
    for (int i = t; i < ROWS * DIM; i += 256) {
        int r = i / DIM, c = i % DIM;
        la[r][c] = in[gbase + i];
        lb[r][c] = tg[gbase + i];
    }
    __syncthreads();

    const int r  = t / LPR;
    const int xo = t % LPR;
    if (xo < OUT) {
        const float* pa = &la[r][xo * ST];
        const float* pb = &lb[r][xo * ST];
        float s0 = 0.f, s1 = 0.f, s2 = 0.f, s3 = 0.f, s4 = 0.f;
        #pragma unroll
        for (int j = 0; j < K; ++j) {
            float a = pa[2 * j], b = pb[2 * j];
            s0 += a; s1 += b; s2 += a * a; s3 += b * b; s4 += a * b;
        }
        int o = (blockIdx.x * ROWS + r) * OUT + xo;
        out[o]            = s0;
        out[n1 + o]       = s1;
        out[2 * n1 + o]   = s2;
        out[3 * n1 + o]   = s3;
        out[4 * n1 + o]   = s4;
    }
}

// ---------------- pass 2: Y box-sum, sliding window ------------------------
// in: 5 planes (B*D, 144, OUT) stride n1. out: 5 planes (B*D, OUT, OUT) stride n2.
// Window shift per output = ST = 2*NT tap steps (dil=2) -> add/remove NT taps.
template<int K, int ST, int OUT, int CHUNK>
__global__ void k2_slide(const float* __restrict__ in, float* __restrict__ out,
                         int n1, int n2)
{
    constexpr int NT  = ST / 2;
    constexpr int NCH = OUT / CHUNK;
    const int total = BATCH * DIM * NCH * OUT;
    int tid = blockIdx.x * 256 + threadIdx.x;
    if (tid >= total) return;
    int xo  = tid % OUT;
    int tmp = tid / OUT;
    int ch  = tmp % NCH;
    int bz  = tmp / NCH;
    const int yo0 = ch * CHUNK;

    const float* base = in + (size_t)bz * DIM * OUT + xo;
    float* ob = out + (size_t)bz * OUT * OUT + xo;

    float s[5];
    #pragma unroll
    for (int q = 0; q < 5; ++q) s[q] = 0.f;
    #pragma unroll
    for (int j = 0; j < K; ++j) {
        int y = ST * yo0 + 2 * j;
        #pragma unroll
        for (int q = 0; q < 5; ++q) s[q] += base[(size_t)q * n1 + y * OUT];
    }
    #pragma unroll
    for (int q = 0; q < 5; ++q) ob[(size_t)q * n2 + yo0 * OUT] = s[q];

    for (int i = 1; i < CHUNK; ++i) {
        int yo = yo0 + i;
        #pragma unroll
        for (int m = 0; m < NT; ++m) {
            int yold = ST * (yo - 1) + 2 * m;
            int ynew = yold + 2 * K;
            #pragma unroll
            for (int q = 0; q < 5; ++q)
                s[q] += base[(size_t)q * n1 + ynew * OUT]
                      - base[(size_t)q * n1 + yold * OUT];
        }
        #pragma unroll
        for (int q = 0; q < 5; ++q) ob[(size_t)q * n2 + yo * OUT] = s[q];
    }
}

// direct Y pass (k=36 only; tiny)
template<int K, int ST, int OUT>
__global__ void k2_direct(const float* __restrict__ in, float* __restrict__ out,
                          int n1, int n2)
{
    const int total = BATCH * DIM * OUT * OUT;
    int tid = blockIdx.x * 256 + threadIdx.x;
    if (tid >= total) return;
    int xo = tid % OUT;
    int yo = (tid / OUT) % OUT;
    int bz = tid / (OUT * OUT);
    const float* base = in + (size_t)bz * DIM * OUT + xo;
    float s[5];
    #pragma unroll
    for (int q = 0; q < 5; ++q) s[q] = 0.f;
    #pragma unroll
    for (int j = 0; j < K; ++j) {
        int y = ST * yo + 2 * j;
        #pragma unroll
        for (int q = 0; q < 5; ++q) s[q] += base[(size_t)q * n1 + y * OUT];
    }
    float* ob = out + (size_t)bz * OUT * OUT + yo * OUT + xo;
    #pragma unroll
    for (int q = 0; q < 5; ++q) ob[(size_t)q * n2] = s[q];
}

__device__ inline float lncc_val(const float s[5], float inv_numel) {
    float cross = s[4] - s[0] * s[1] * inv_numel;
    float ivar  = s[2] - s[0] * s[0] * inv_numel;
    float tvar  = s[3] - s[1] * s[1] * inv_numel;
    return (cross * cross) / (ivar * tvar + EPS);
}

__device__ inline void block_reduce_atomic(float acc, float factor, float* out) {
    #pragma unroll
    for (int off = 32; off > 0; off >>= 1) acc += __shfl_down(acc, off, 64);
    __shared__ float sm[4];
    int lane = threadIdx.x & 63, wid = threadIdx.x >> 6;
    if (lane == 0) sm[wid] = acc;
    __syncthreads();
    if (threadIdx.x == 0)
        atomicAdd(out, -factor * (sm[0] + sm[1] + sm[2] + sm[3]));
}

// ---------------- pass 3: Z box-sum + LNCC, sliding (k=9) -----------------
// in: 5 planes (B, 144, OUT, OUT) stride n2.
template<int K, int ST, int OUT, int CHUNK>
__global__ void k3_slide(const float* __restrict__ in, float* __restrict__ out,
                         int n2, float inv_numel, float factor)
{
    constexpr int NCH = OUT / CHUNK;
    const int total = BATCH * NCH * OUT * OUT;
    int tid = blockIdx.x * 256 + threadIdx.x;
    float acc = 0.f;
    if (tid < total) {
        int xo = tid % OUT;
        int yo = (tid / OUT) % OUT;
        int ch = (tid / (OUT * OUT)) % NCH;
        int b  = tid / (OUT * OUT * NCH);
        const int zo0 = ch * CHUNK;
        const int OO = OUT * OUT;
        const float* base = in + (size_t)b * DIM * OO + yo * OUT + xo;

        float s[5];
        #pragma unroll
        for (int q = 0; q < 5; ++q) s[q] = 0.f;
        #pragma unroll
        for (int j = 0; j < K; ++j) {
            int z = ST * zo0 + 2 * j;
            #pragma unroll
            for (int q = 0; q < 5; ++q) s[q] += base[(size_t)q * n2 + z * OO];
        }
        acc += lncc_val(s, inv_numel);
        for (int i = 1; i < CHUNK; ++i) {
            int zo = zo0 + i;
            int zold = ST * (zo - 1);
            int znew = zold + 2 * K;
            #pragma unroll
            for (int q = 0; q < 5; ++q)
                s[q] += base[(size_t)q * n2 + znew * OO]
                      - base[(size_t)q * n2 + zold * OO];
            acc += lncc_val(s, inv_numel);
        }
    }
    block_reduce_atomic(acc, factor, out);
}

// direct Z pass + LNCC (k=18: TSPLIT=1, k=36: TSPLIT=4)
template<int K, int ST, int OUT, int TSPLIT>
__global__ void k3_direct(const float* __restrict__ in, float* __restrict__ out,
                          int n2, float inv_numel, float factor)
{
    const int total = BATCH * OUT * OUT * OUT * TSPLIT;
    int tid = blockIdx.x * 256 + threadIdx.x;
    float acc = 0.f;
    if (tid < total) {
        int sp   = tid % TSPLIT;
        int rest = tid / TSPLIT;
        int xo = rest % OUT;
        int yo = (rest / OUT) % OUT;
        int zo = (rest / (OUT * OUT)) % OUT;
        int b  = rest / (OUT * OUT * OUT);
        const int OO = OUT * OUT;
        const float* base = in + (size_t)b * DIM * OO + yo * OUT + xo;

        float s[5];
        #pragma unroll
        for (int q = 0; q < 5; ++q) s[q] = 0.f;
        #pragma unroll
        for (int j = 0; j < K; ++j) {
            if ((j % TSPLIT) == sp) {
                int z = ST * zo + 2 * j;
                #pragma unroll
                for (int q = 0; q < 5; ++q) s[q] += base[(size_t)q * n2 + z * OO];
            }
        }
        if (TSPLIT > 1) {
            #pragma unroll
            for (int off = 1; off < TSPLIT; off <<= 1) {
                #pragma unroll
                for (int q = 0; q < 5; ++q) s[q] += __shfl_xor(s[q], off, 64);
            }
        }
        if (sp == 0) acc = lncc_val(s, inv_numel);
    }
    block_reduce_atomic(acc, factor, out);
}

// --------------------------------------------------------------------------
extern "C" void kernel_launch(void* const* d_in, const int* in_sizes, int n_in,
                              void* d_out, int out_size, void* d_ws, size_t ws_size,
                              hipStream_t stream) {
    const float* input  = (const float*)d_in[0];
    const float* target = (const float*)d_in[1];
    float* out = (float*)d_out;

    const int N1MAX = NROWS * 64;                 // 5,308,416
    float* buf1 = (float*)d_ws;
    float* buf2 = buf1 + (size_t)5 * N1MAX;

    k_init_out<<<1, 64, 0, stream>>>(out);

    // ---- scale 0: K=9, ST=2, OUT=64 ----
    {
        constexpr int K = 9, ST = 2, OUT = 64;
        int n1 = NROWS * OUT;                     // 5,308,416
        int n2 = BATCH * DIM * OUT * OUT;         // 2,359,296
        float inv = 1.0f / (float)(K * K * K);
        float factor = 0.1f / (float)(OUT * OUT * OUT);
        k1_x<K, ST, OUT, 4, 64><<<NROWS / 4, 256, 0, stream>>>(input, target, buf1, n1);
        int t2 = BATCH * DIM * (OUT / 16) * OUT;  // 147,456
        k2_slide<K, ST, OUT, 16><<<(t2 + 255) / 256, 256, 0, stream>>>(buf1, buf2, n1, n2);
        int t3 = BATCH * (OUT / 16) * OUT * OUT;  // 65,536
        k3_slide<K, ST, OUT, 16><<<(t3 + 255) / 256, 256, 0, stream>>>(buf2, out, n2, inv, factor);
    }
    // ---- scale 1: K=18, ST=4, OUT=28 ----
    {
        constexpr int K = 18, ST = 4, OUT = 28;
        int n1 = NROWS * OUT;                     // 2,322,432
        int n2 = BATCH * DIM * OUT * OUT;         // 451,584
        float inv = 1.0f / (float)(K * K * K);
        float factor = 0.3f / (float)(OUT * OUT * OUT);
        k1_x<K, ST, OUT, 8, 32><<<NROWS / 8, 256, 0, stream>>>(input, target, buf1, n1);
        int t2 = BATCH * DIM * (OUT / 7) * OUT;   // 64,512
        k2_slide<K, ST, OUT, 7><<<(t2 + 255) / 256, 256, 0, stream>>>(buf1, buf2, n1, n2);
        int t3 = BATCH * OUT * OUT * OUT;         // 87,808
        k3_direct<K, ST, OUT, 1><<<(t3 + 255) / 256, 256, 0, stream>>>(buf2, out, n2, inv, factor);
    }
    // ---- scale 2: K=36, ST=9, OUT=9 ----
    {
        constexpr int K = 36, ST = 9, OUT = 9;
        int n1 = NROWS * OUT;                     // 746,496
        int n2 = BATCH * DIM * OUT * OUT;         // 46,656
        float inv = 1.0f / (float)(K * K * K);
        float factor = 0.6f / (float)(OUT * OUT * OUT);
        k1_x<K, ST, OUT, 16, 16><<<NROWS / 16, 256, 0, stream>>>(input, target, buf1, n1);
        int t2 = BATCH * DIM * OUT * OUT;         // 46,656
        k2_direct<K, ST, OUT><<<(t2 + 255) / 256, 256, 0, stream>>>(buf1, buf2, n1, n2);
        int t3 = BATCH * OUT * OUT * OUT * 4;     // 11,664
        k3_direct<K, ST, OUT, 4><<<(t3 + 255) / 256, 256, 0, stream>>>(buf2, out, n2, inv, factor);
    }
}

// Round 3
// 176.612 us; speedup vs baseline: 2.2657x; 1.1805x over previous
//
#include <hip/hip_runtime.h>

// LNCC multi-scale loss, fp32, (4,1,144,144,144) -> scalar.
// Structure: fused X-pass (all 3 scales, one input read) -> merged Y-pass
// (all scales, one launch) -> merged Z-pass + LNCC + reduction (one launch).

constexpr int BATCH = 4;
constexpr int DIM   = 144;
constexpr int NROWS = BATCH * DIM * DIM;   // 82944 rows along X
constexpr float EPS = 1e-5f;

// plane strides (elements) per scale
constexpr int N1A = NROWS * 64;            // 5,308,416
constexpr int N1B = NROWS * 28;            // 2,322,432
constexpr int N1C = NROWS * 9;             //   746,496
constexpr int N2A = BATCH * DIM * 64 * 64; // 2,359,296
constexpr int N2B = BATCH * DIM * 28 * 28; //   451,584
constexpr int N2C = BATCH * DIM * 9 * 9;   //    46,656

__global__ void k_init_out(float* out) {
    if (threadIdx.x == 0 && blockIdx.x == 0) out[0] = 4.0f;
}

// ======================= device bodies =====================================

__device__ __forceinline__ float lncc_val(const float s[5], float inv_numel) {
    float cross = s[4] - s[0] * s[1] * inv_numel;
    float ivar  = s[2] - s[0] * s[0] * inv_numel;
    float tvar  = s[3] - s[1] * s[1] * inv_numel;
    return (cross * cross) / (ivar * tvar + EPS);
}

__device__ __forceinline__ void block_reduce_atomic(float acc, float factor, float* out) {
    #pragma unroll
    for (int off = 32; off > 0; off >>= 1) acc += __shfl_down(acc, off, 64);
    __shared__ float sm[4];
    int lane = threadIdx.x & 63, wid = threadIdx.x >> 6;
    if (lane == 0) sm[wid] = acc;
    __syncthreads();
    if (threadIdx.x == 0)
        atomicAdd(out, -factor * (sm[0] + sm[1] + sm[2] + sm[3]));
}

// ---- pass2 sliding-window body (stride multiple of dilation) --------------
template<int K, int ST, int OUT, int CHUNK>
__device__ __forceinline__ void k2s_body(int tid, const float* __restrict__ in,
                                         float* __restrict__ out, int n1, int n2)
{
    constexpr int NT  = ST / 2;
    constexpr int NCH = OUT / CHUNK;
    const int total = BATCH * DIM * NCH * OUT;
    if (tid >= total) return;
    int xo  = tid % OUT;
    int tmp = tid / OUT;
    int ch  = tmp % NCH;
    int bz  = tmp / NCH;
    const int yo0 = ch * CHUNK;

    const float* base = in + (size_t)bz * DIM * OUT + xo;
    float* ob = out + (size_t)bz * OUT * OUT + xo;

    float s[5] = {0.f, 0.f, 0.f, 0.f, 0.f};
    #pragma unroll
    for (int j = 0; j < K; ++j) {
        int y = ST * yo0 + 2 * j;
        #pragma unroll
        for (int q = 0; q < 5; ++q) s[q] += base[(size_t)q * n1 + y * OUT];
    }
    #pragma unroll
    for (int q = 0; q < 5; ++q) ob[(size_t)q * n2 + yo0 * OUT] = s[q];

    #pragma unroll
    for (int i = 1; i < CHUNK; ++i) {
        #pragma unroll
        for (int m = 0; m < NT; ++m) {
            int yold = ST * (yo0 + i - 1) + 2 * m;
            int ynew = yold + 2 * K;
            #pragma unroll
            for (int q = 0; q < 5; ++q)
                s[q] += base[(size_t)q * n1 + ynew * OUT]
                      - base[(size_t)q * n1 + yold * OUT];
        }
        #pragma unroll
        for (int q = 0; q < 5; ++q) ob[(size_t)q * n2 + (yo0 + i) * OUT] = s[q];
    }
}

// ---- pass2 direct body with tap-split --------------------------------------
template<int K, int ST, int OUT, int TS>
__device__ __forceinline__ void k2d_body(int tid, const float* __restrict__ in,
                                         float* __restrict__ out, int n1, int n2)
{
    const int total = BATCH * DIM * OUT * OUT * TS;   // multiple of 64
    if (tid >= total) return;
    int sp   = tid % TS;
    int rest = tid / TS;
    int xo = rest % OUT;
    int yo = (rest / OUT) % OUT;
    int bz = rest / (OUT * OUT);
    const float* base = in + (size_t)bz * DIM * OUT + xo;

    float s[5] = {0.f, 0.f, 0.f, 0.f, 0.f};
    #pragma unroll
    for (int j = 0; j < K; ++j) {
        if ((j % TS) == sp) {
            int y = ST * yo + 2 * j;
            #pragma unroll
            for (int q = 0; q < 5; ++q) s[q] += base[(size_t)q * n1 + y * OUT];
        }
    }
    if (TS > 1) {
        #pragma unroll
        for (int off = 1; off < TS; off <<= 1) {
            #pragma unroll
            for (int q = 0; q < 5; ++q) s[q] += __shfl_xor(s[q], off, 64);
        }
    }
    if (sp == 0) {
        float* ob = out + (size_t)bz * OUT * OUT + yo * OUT + xo;
        #pragma unroll
        for (int q = 0; q < 5; ++q) ob[(size_t)q * n2] = s[q];
    }
}

// ---- pass3 sliding body + LNCC ---------------------------------------------
template<int K, int ST, int OUT, int CHUNK>
__device__ __forceinline__ void k3s_body(int tid, const float* __restrict__ in,
                                         float* __restrict__ out, int n2,
                                         float inv_numel, float factor)
{
    constexpr int NCH = OUT / CHUNK;
    const int total = BATCH * NCH * OUT * OUT;
    float acc = 0.f;
    if (tid < total) {
        int xo = tid % OUT;
        int yo = (tid / OUT) % OUT;
        int ch = (tid / (OUT * OUT)) % NCH;
        int b  = tid / (OUT * OUT * NCH);
        const int zo0 = ch * CHUNK;
        const int OO = OUT * OUT;
        const float* base = in + (size_t)b * DIM * OO + yo * OUT + xo;

        float s[5] = {0.f, 0.f, 0.f, 0.f, 0.f};
        #pragma unroll
        for (int j = 0; j < K; ++j) {
            int z = ST * zo0 + 2 * j;
            #pragma unroll
            for (int q = 0; q < 5; ++q) s[q] += base[(size_t)q * n2 + z * OO];
        }
        acc += lncc_val(s, inv_numel);
        #pragma unroll
        for (int i = 1; i < CHUNK; ++i) {
            int zold = ST * (zo0 + i - 1);
            int znew = zold + 2 * K;
            #pragma unroll
            for (int q = 0; q < 5; ++q)
                s[q] += base[(size_t)q * n2 + znew * OO]
                      - base[(size_t)q * n2 + zold * OO];
            acc += lncc_val(s, inv_numel);
        }
    }
    block_reduce_atomic(acc, factor, out);
}

// ---- pass3 direct body + tap-split + LNCC ----------------------------------
template<int K, int ST, int OUT, int TS>
__device__ __forceinline__ void k3d_body(int tid, const float* __restrict__ in,
                                         float* __restrict__ out, int n2,
                                         float inv_numel, float factor)
{
    const int total = BATCH * OUT * OUT * OUT * TS;
    float acc = 0.f;
    if (tid < total) {     // totals are multiples of 64 -> full waves active
        int sp   = tid % TS;
        int rest = tid / TS;
        int xo = rest % OUT;
        int yo = (rest / OUT) % OUT;
        int zo = (rest / (OUT * OUT)) % OUT;
        int b  = rest / (OUT * OUT * OUT);
        const int OO = OUT * OUT;
        const float* base = in + (size_t)b * DIM * OO + yo * OUT + xo;

        float s[5] = {0.f, 0.f, 0.f, 0.f, 0.f};
        #pragma unroll
        for (int j = 0; j < K; ++j) {
            if ((j % TS) == sp) {
                int z = ST * zo + 2 * j;
                #pragma unroll
                for (int q = 0; q < 5; ++q) s[q] += base[(size_t)q * n2 + z * OO];
            }
        }
        if (TS > 1) {
            #pragma unroll
            for (int off = 1; off < TS; off <<= 1) {
                #pragma unroll
                for (int q = 0; q < 5; ++q) s[q] += __shfl_xor(s[q], off, 64);
            }
        }
        if (sp == 0) acc = lncc_val(s, inv_numel);
    }
    block_reduce_atomic(acc, factor, out);
}

// ======================= pass 1 =============================================

// Fused X-pass: one input read, outputs for all three scales.
__global__ void k1_fused(const float* __restrict__ in, const float* __restrict__ tg,
                         float* __restrict__ oa, float* __restrict__ ob,
                         float* __restrict__ oc)
{
    __shared__ float la[4][DIM + 1];
    __shared__ float lb[4][DIM + 1];
    const int t = threadIdx.x;
    const int gbase = blockIdx.x * (4 * DIM);
    for (int i = t; i < 4 * DIM; i += 256) {
        la[i / DIM][i % DIM] = in[gbase + i];
        lb[i / DIM][i % DIM] = tg[gbase + i];
    }
    __syncthreads();

    // scale 0: K=9, ST=2, OUT=64 — all 256 threads
    {
        int r = t >> 6, xo = t & 63;
        const float* pa = &la[r][xo * 2];
        const float* pb = &lb[r][xo * 2];
        float s0 = 0.f, s1 = 0.f, s2 = 0.f, s3 = 0.f, s4 = 0.f;
        #pragma unroll
        for (int j = 0; j < 9; ++j) {
            float a = pa[2 * j], b = pb[2 * j];
            s0 += a; s1 += b; s2 += a * a; s3 += b * b; s4 += a * b;
        }
        int o = (blockIdx.x * 4 + r) * 64 + xo;
        oa[o] = s0; oa[N1A + o] = s1; oa[2 * N1A + o] = s2;
        oa[3 * N1A + o] = s3; oa[4 * N1A + o] = s4;
    }
    // scale 1: K=18, ST=4, OUT=28 — threads 0..127
    if (t < 128) {
        int r = t >> 5, xo = t & 31;
        if (xo < 28) {
            const float* pa = &la[r][xo * 4];
            const float* pb = &lb[r][xo * 4];
            float s0 = 0.f, s1 = 0.f, s2 = 0.f, s3 = 0.f, s4 = 0.f;
            #pragma unroll
            for (int j = 0; j < 18; ++j) {
                float a = pa[2 * j], b = pb[2 * j];
                s0 += a; s1 += b; s2 += a * a; s3 += b * b; s4 += a * b;
            }
            int o = (blockIdx.x * 4 + r) * 28 + xo;
            ob[o] = s0; ob[N1B + o] = s1; ob[2 * N1B + o] = s2;
            ob[3 * N1B + o] = s3; ob[4 * N1B + o] = s4;
        }
    }
    // scale 2: K=36, ST=9, OUT=9 — threads 0..63
    if (t < 64) {
        int r = t >> 4, xo = t & 15;
        if (xo < 9) {
            const float* pa = &la[r][xo * 9];
            const float* pb = &lb[r][xo * 9];
            float s0 = 0.f, s1 = 0.f, s2 = 0.f, s3 = 0.f, s4 = 0.f;
            #pragma unroll
            for (int j = 0; j < 36; ++j) {
                float a = pa[2 * j], b = pb[2 * j];
                s0 += a; s1 += b; s2 += a * a; s3 += b * b; s4 += a * b;
            }
            int o = (blockIdx.x * 4 + r) * 9 + xo;
            oc[o] = s0; oc[N1C + o] = s1; oc[2 * N1C + o] = s2;
            oc[3 * N1C + o] = s3; oc[4 * N1C + o] = s4;
        }
    }
}

// per-scale X-pass (fallback path)
template<int K, int ST, int OUT, int ROWS, int LPR>
__global__ void k1_x(const float* __restrict__ in, const float* __restrict__ tg,
                     float* __restrict__ out, int n1)
{
    __shared__ float la[ROWS][DIM + 1];
    __shared__ float lb[ROWS][DIM + 1];
    const int t = threadIdx.x;
    const int gbase = blockIdx.x * (ROWS * DIM);
    for (int i = t; i < ROWS * DIM; i += 256) {
        la[i / DIM][i % DIM] = in[gbase + i];
        lb[i / DIM][i % DIM] = tg[gbase + i];
    }
    __syncthreads();
    const int r  = t / LPR;
    const int xo = t % LPR;
    if (r < ROWS && xo < OUT) {
        const float* pa = &la[r][xo * ST];
        const float* pb = &lb[r][xo * ST];
        float s0 = 0.f, s1 = 0.f, s2 = 0.f, s3 = 0.f, s4 = 0.f;
        #pragma unroll
        for (int j = 0; j < K; ++j) {
            float a = pa[2 * j], b = pb[2 * j];
            s0 += a; s1 += b; s2 += a * a; s3 += b * b; s4 += a * b;
        }
        int o = (blockIdx.x * ROWS + r) * OUT + xo;
        out[o] = s0; out[n1 + o] = s1; out[2 * n1 + o] = s2;
        out[3 * n1 + o] = s3; out[4 * n1 + o] = s4;
    }
}

// ======================= merged pass 2 / pass 3 =============================

constexpr int B_K2A = (BATCH * DIM * (64 / 8) * 64) / 256;        // 1152
constexpr int B_K2B = (BATCH * DIM * (28 / 4) * 28) / 256;        // 441
constexpr int B_K2C = (BATCH * DIM * 9 * 9 * 8) / 256;            // 1458
constexpr int B_K3A = (BATCH * (64 / 8) * 64 * 64) / 256;         // 512
constexpr int B_K3B = (BATCH * 28 * 28 * 28 * 8) / 256;           // 2744
constexpr int B_K3C = (BATCH * 9 * 9 * 9 * 16 + 255) / 256;       // 183

__global__ void k2_all(const float* __restrict__ b1a, const float* __restrict__ b1b,
                       const float* __restrict__ b1c,
                       float* __restrict__ b2a, float* __restrict__ b2b,
                       float* __restrict__ b2c)
{
    int blk = blockIdx.x;
    if (blk < B_K2A) {
        k2s_body<9, 2, 64, 8>(blk * 256 + threadIdx.x, b1a, b2a, N1A, N2A);
    } else if (blk < B_K2A + B_K2B) {
        k2s_body<18, 4, 28, 4>((blk - B_K2A) * 256 + threadIdx.x, b1b, b2b, N1B, N2B);
    } else {
        k2d_body<36, 9, 9, 8>((blk - B_K2A - B_K2B) * 256 + threadIdx.x, b1c, b2c, N1C, N2C);
    }
}

__global__ void k3_all(const float* __restrict__ b2a, const float* __restrict__ b2b,
                       const float* __restrict__ b2c, float* __restrict__ out)
{
    int blk = blockIdx.x;
    if (blk < B_K3A) {
        k3s_body<9, 2, 64, 8>(blk * 256 + threadIdx.x, b2a, out, N2A,
                              1.0f / 729.0f, 0.1f / 262144.0f);
    } else if (blk < B_K3A + B_K3B) {
        k3d_body<18, 4, 28, 8>((blk - B_K3A) * 256 + threadIdx.x, b2b, out, N2B,
                               1.0f / 5832.0f, 0.3f / 21952.0f);
    } else {
        k3d_body<36, 9, 9, 16>((blk - B_K3A - B_K3B) * 256 + threadIdx.x, b2c, out, N2C,
                               1.0f / 46656.0f, 0.6f / 729.0f);
    }
}

// ---- per-scale wrappers (fallback path) ------------------------------------
template<int K, int ST, int OUT, int CHUNK>
__global__ void g_k2s(const float* __restrict__ in, float* __restrict__ out,
                      int n1, int n2)
{ k2s_body<K, ST, OUT, CHUNK>(blockIdx.x * 256 + threadIdx.x, in, out, n1, n2); }

template<int K, int ST, int OUT, int TS>
__global__ void g_k2d(const float* __restrict__ in, float* __restrict__ out,
                      int n1, int n2)
{ k2d_body<K, ST, OUT, TS>(blockIdx.x * 256 + threadIdx.x, in, out, n1, n2); }

template<int K, int ST, int OUT, int CHUNK>
__global__ void g_k3s(const float* __restrict__ in, float* __restrict__ out,
                      int n2, float inv, float f)
{ k3s_body<K, ST, OUT, CHUNK>(blockIdx.x * 256 + threadIdx.x, in, out, n2, inv, f); }

template<int K, int ST, int OUT, int TS>
__global__ void g_k3d(const float* __restrict__ in, float* __restrict__ out,
                      int n2, float inv, float f)
{ k3d_body<K, ST, OUT, TS>(blockIdx.x * 256 + threadIdx.x, in, out, n2, inv, f); }

// ============================================================================
extern "C" void kernel_launch(void* const* d_in, const int* in_sizes, int n_in,
                              void* d_out, int out_size, void* d_ws, size_t ws_size,
                              hipStream_t stream) {
    const float* input  = (const float*)d_in[0];
    const float* target = (const float*)d_in[1];
    float* out = (float*)d_out;

    k_init_out<<<1, 64, 0, stream>>>(out);

    const size_t needFull = (size_t)5 * (N1A + N1B + N1C + N2A + N2B + N2C) * 4;

    if (ws_size >= needFull) {
        // ---- full concurrent layout: 3 launches after init ----
        float* b1a = (float*)d_ws;
        float* b1b = b1a + (size_t)5 * N1A;
        float* b1c = b1b + (size_t)5 * N1B;
        float* b2a = b1c + (size_t)5 * N1C;
        float* b2b = b2a + (size_t)5 * N2A;
        float* b2c = b2b + (size_t)5 * N2B;

        k1_fused<<<NROWS / 4, 256, 0, stream>>>(input, target, b1a, b1b, b1c);
        k2_all<<<B_K2A + B_K2B + B_K2C, 256, 0, stream>>>(b1a, b1b, b1c, b2a, b2b, b2c);
        k3_all<<<B_K3A + B_K3B + B_K3C, 256, 0, stream>>>(b2a, b2b, b2c, out);
    } else {
        // ---- sequential fallback (R1-proven 153 MB layout) ----
        float* buf1 = (float*)d_ws;
        float* buf2 = buf1 + (size_t)5 * N1A;

        // scale 0: K=9, ST=2, OUT=64
        k1_x<9, 2, 64, 4, 64><<<NROWS / 4, 256, 0, stream>>>(input, target, buf1, N1A);
        g_k2s<9, 2, 64, 8><<<B_K2A, 256, 0, stream>>>(buf1, buf2, N1A, N2A);
        g_k3s<9, 2, 64, 8><<<B_K3A, 256, 0, stream>>>(buf2, out, N2A,
                                                      1.0f / 729.0f, 0.1f / 262144.0f);
        // scale 1: K=18, ST=4, OUT=28
        k1_x<18, 4, 28, 8, 32><<<NROWS / 8, 256, 0, stream>>>(input, target, buf1, N1B);
        g_k2s<18, 4, 28, 4><<<B_K2B, 256, 0, stream>>>(buf1, buf2, N1B, N2B);
        g_k3d<18, 4, 28, 8><<<B_K3B, 256, 0, stream>>>(buf2, out, N2B,
                                                       1.0f / 5832.0f, 0.3f / 21952.0f);
        // scale 2: K=36, ST=9, OUT=9
        k1_x<36, 9, 9, 16, 16><<<NROWS / 16, 256, 0, stream>>>(input, target, buf1, N1C);
        g_k2d<36, 9, 9, 8><<<B_K2C, 256, 0, stream>>>(buf1, buf2, N1C, N2C);
        g_k3d<36, 9, 9, 16><<<B_K3C, 256, 0, stream>>>(buf2, out, N2C,
                                                       1.0f / 46656.0f, 0.6f / 729.0f);
    }
}